// Round 12
// baseline (203.292 us; speedup 1.0000x reference)
//
#include <hip/hip_runtime.h>

// ---------------------------------------------------------------------------
// Self-attention (B=4, N=2048, D=1024) on MI355X — fp16, round 12:
// Algebraic fold: S = x·(Wq^T Wk)·x^T + v_j (+softmax-invariant terms).
// K-projection eliminated: Mt = Wk^T·Wq (tiny GEMM), T = x·Mt, S = T·x^T + v.
// GEMM core = R8's proven 2-phase 128^2/BK=64 counted-vmcnt kernel, untouched.
// ---------------------------------------------------------------------------

typedef _Float16 hfx8 __attribute__((ext_vector_type(8)));
typedef _Float16 hfx4 __attribute__((ext_vector_type(4)));
typedef float fx4 __attribute__((ext_vector_type(4)));

__device__ __forceinline__ void load_lds16(const void* g, void* l) {
    __builtin_amdgcn_global_load_lds(
        (const __attribute__((address_space(1))) void*)g,
        (__attribute__((address_space(3))) void*)l, 16, 0, 0);
}

template <int N> __device__ __forceinline__ void vmwait() {
    if constexpr (N == 8) asm volatile("s_waitcnt vmcnt(8)" ::: "memory");
    else asm volatile("s_waitcnt vmcnt(0)" ::: "memory");
}

// bijective XCD-chunked grid remap (T1, m204). Requires nwg % 8 == 0.
__device__ __forceinline__ void xcd_remap(int& x, int& y, int& z) {
    const int gx = gridDim.x, gy = gridDim.y;
    const int lin = blockIdx.x + gx * (blockIdx.y + gy * blockIdx.z);
    const int cpx = (gx * gy * gridDim.z) >> 3;
    const int w = (lin & 7) * cpx + (lin >> 3);
    x = w % gx;
    y = (w / gx) % gy;
    z = w / (gx * gy);
}

// ---------------------------------------------------------------------------
// Wq, Wk fp32 [1024][1024] -> WqT, WkT fp16 transposed [1024][1024].
// 64x64 LDS tile, grid (16,16,2).
// ---------------------------------------------------------------------------
__global__ __launch_bounds__(256) void transpose_w_kernel(
    const float* __restrict__ Wq, const float* __restrict__ Wk,
    _Float16* __restrict__ WqT, _Float16* __restrict__ WkT)
{
    const float* src = blockIdx.z ? Wk : Wq;
    _Float16* dst = blockIdx.z ? WkT : WqT;
    const int d0 = blockIdx.x * 64;   // src col / dst row
    const int k0 = blockIdx.y * 64;   // src row / dst col
    __shared__ float t[64][65];
    const int tid = threadIdx.x;
#pragma unroll
    for (int i = 0; i < 4; ++i) {
        const int r = i * 16 + (tid >> 4);
        const int c = (tid & 15) * 4;
        const float4 v = *(const float4*)&src[(long)(k0 + r) * 1024 + d0 + c];
        t[r][c] = v.x; t[r][c + 1] = v.y; t[r][c + 2] = v.z; t[r][c + 3] = v.w;
    }
    __syncthreads();
#pragma unroll
    for (int i = 0; i < 2; ++i) {
        const int d = i * 32 + (tid >> 3);
        const int k = (tid & 7) * 8;
        hfx8 h;
#pragma unroll
        for (int j = 0; j < 8; ++j) h[j] = (_Float16)t[k + j][d];
        *(hfx8*)&dst[(long)(d0 + d) * 1024 + k0 + k] = h;
    }
}

// ---------------------------------------------------------------------------
// w2[d] = sum_k bq[k] * Wk[k][d]   (fp32, coalesced over d)
// ---------------------------------------------------------------------------
__global__ __launch_bounds__(256) void w2_kernel(
    const float* __restrict__ bq, const float* __restrict__ Wk, float* __restrict__ w2)
{
    const int d = blockIdx.x * 256 + threadIdx.x;
    float a = 0.f;
    for (int k = 0; k < 1024; ++k)
        a = fmaf(bq[k], Wk[(long)k * 1024 + d], a);
    w2[d] = a;
}

// ---------------------------------------------------------------------------
// conv: blocks [0,8192): x row b -> xs fp16 AND v[b] = dot(x_b, w2).
//       blocks [8192,9216): Wv -> Wvh fp16.
// ---------------------------------------------------------------------------
__global__ __launch_bounds__(256) void conv_all_kernel(
    const float4* __restrict__ x, _Float16* __restrict__ xs,
    const float4* __restrict__ wv, _Float16* __restrict__ wvh,
    const float* __restrict__ w2, float* __restrict__ v)
{
    const int b = blockIdx.x;
    const int tid = threadIdx.x;
    if (b < 8192) {
        const long i = (long)b * 256 + tid;
        const float4 xv = x[i];
        hfx4 h;
        h[0] = (_Float16)xv.x; h[1] = (_Float16)xv.y;
        h[2] = (_Float16)xv.z; h[3] = (_Float16)xv.w;
        *(hfx4*)&xs[i * 4] = h;
        const float4 wval = *(const float4*)&w2[tid * 4];
        float dot = xv.x * wval.x + xv.y * wval.y + xv.z * wval.z + xv.w * wval.w;
#pragma unroll
        for (int o = 32; o; o >>= 1) dot += __shfl_xor(dot, o, 64);
        __shared__ float red[4];
        if ((tid & 63) == 0) red[tid >> 6] = dot;
        __syncthreads();
        if (tid == 0) v[b] = red[0] + red[1] + red[2] + red[3];
    } else {
        const long i = (long)(b - 8192) * 256 + tid;
        const float4 wv4 = wv[i];
        hfx4 h;
        h[0] = (_Float16)wv4.x; h[1] = (_Float16)wv4.y;
        h[2] = (_Float16)wv4.z; h[3] = (_Float16)wv4.w;
        *(hfx4*)&wvh[i * 4] = h;
    }
}

// ---------------------------------------------------------------------------
// Proven 2-phase pipelined GEMM (R8). BM=BN=128, BK=64, 256 thr = 4 waves,
// 64 KB LDS -> 2 blocks/CU. Counted-vmcnt, raw s_barrier, T2 swizzle, T5, T1.
// C = A·B^T (A [M x K] lda, B [N x K] ldb).
// OMODE 0: fp32 out = alpha*acc + cbias[z*2048+col] -> outF + z*sCz; B=B0+z*sBz
// OMODE 1: proj: z=0: T = acc -> oH0 fp16 [8192][1024] (B=B0=Mt);
//                z=1: V = acc + bias -> oH1 transposed [4][1024][2048] (B=B1)
// OMODE 2: plain fp16 out -> oH0[row*ldc+col] (M-gemm)
// ---------------------------------------------------------------------------
template <int OMODE>
__global__ __launch_bounds__(256, 2) void gemm2(
    const _Float16* __restrict__ A,
    const _Float16* __restrict__ B0, const _Float16* __restrict__ B1,
    const float* __restrict__ bias, const float* __restrict__ cbias,
    float* __restrict__ outF, _Float16* __restrict__ oH0, _Float16* __restrict__ oH1,
    int K, int lda, int ldb, int ldc, float alpha,
    long sAz, long sBz, long sCz)
{
    constexpr int BM = 128, BN = 128, BK = 64;
    constexpr int LPT = 8;

    __shared__ __attribute__((aligned(16))) _Float16 lds[2][(BM + BN) * BK];

    int bx, by, z;
    xcd_remap(bx, by, z);

    A += (long)z * sAz;
    const _Float16* B = (OMODE == 1) ? (z == 0 ? B0 : B1) : B0 + (long)z * sBz;

    const int tid = threadIdx.x;
    const int lane = tid & 63;
    const int wv = tid >> 6;
    const int wr = wv >> 1, wc = wv & 1;
    const int lr = lane & 15, lk = lane >> 4;

    const long m0 = (long)by * BM;
    const long n0 = (long)bx * BN;

    fx4 acc[4][4] = {};

    auto STAGE = [&](int kt, int b) {
#pragma unroll
        for (int i = 0; i < LPT; ++i) {
            const int c = i * 256 + tid;
            if (i < 4) {
                const int row = c >> 3, slot = c & 7;
                load_lds16(A + (m0 + row) * (long)lda + kt + ((slot ^ (row & 7)) << 3),
                           &lds[b][c * 8]);
            } else {
                const int c2 = c - 1024;
                const int row = c2 >> 3, slot = c2 & 7;
                load_lds16(B + (n0 + row) * (long)ldb + kt + ((slot ^ (row & 7)) << 3),
                           &lds[b][BM * BK + c2 * 8]);
            }
        }
    };

    const int NT = K / BK;
    STAGE(0, 0);
    STAGE(BK, 1);
    vmwait<8>();
    __builtin_amdgcn_s_barrier();
    __builtin_amdgcn_sched_barrier(0);

    const int rA0 = wr * 64 + lr;
    const int rB0 = wc * 64 + lr;
    const int eA = (rA0 & 7) << 3;
    const int eB = (rB0 & 7) << 3;

    for (int t = 0; t < NT; ++t) {
        const _Float16* LA = &lds[t & 1][0];
        const _Float16* LB = LA + BM * BK;

        hfx8 bfr[4][2];
#pragma unroll
        for (int nf = 0; nf < 4; ++nf)
#pragma unroll
            for (int ks = 0; ks < 2; ++ks)
                bfr[nf][ks] = *(const hfx8*)&LB[(rB0 + nf * 16) * BK + ((ks * 32 + lk * 8) ^ eB)];

#pragma unroll
        for (int q = 0; q < 4; ++q) {
            hfx8 afr[2];
#pragma unroll
            for (int ks = 0; ks < 2; ++ks)
                afr[ks] = *(const hfx8*)&LA[(rA0 + q * 16) * BK + ((ks * 32 + lk * 8) ^ eA)];
            __builtin_amdgcn_s_setprio(1);
#pragma unroll
            for (int nf = 0; nf < 4; ++nf)
#pragma unroll
                for (int ks = 0; ks < 2; ++ks)
                    acc[q][nf] = __builtin_amdgcn_mfma_f32_16x16x32_f16(
                        afr[ks], bfr[nf][ks], acc[q][nf], 0, 0, 0);
            __builtin_amdgcn_s_setprio(0);
        }

        __builtin_amdgcn_s_barrier();
        if (t + 2 < NT) {
            STAGE((t + 2) * BK, t & 1);
            vmwait<8>();
        } else {
            vmwait<0>();
        }
        __builtin_amdgcn_s_barrier();
        __builtin_amdgcn_sched_barrier(0);
    }

    // epilogue. D frag: col = lane&15, row = lk*4 + j
#pragma unroll
    for (int mf = 0; mf < 4; ++mf) {
#pragma unroll
        for (int nf = 0; nf < 4; ++nf) {
            const long row0 = m0 + wr * 64 + mf * 16 + lk * 4;
            const long col = n0 + wc * 64 + nf * 16 + lr;
            if constexpr (OMODE == 0) {
                float* oz = outF + (long)z * sCz;
                const float cb = cbias ? cbias[(long)z * 2048 + col] : 0.0f;
#pragma unroll
                for (int j = 0; j < 4; ++j)
                    oz[(row0 + j) * (long)ldc + col] = alpha * acc[mf][nf][j] + cb;
            } else if constexpr (OMODE == 2) {
#pragma unroll
                for (int j = 0; j < 4; ++j)
                    oH0[(row0 + j) * (long)ldc + col] = (_Float16)(alpha * acc[mf][nf][j]);
            } else {
                if (z == 0) {
#pragma unroll
                    for (int j = 0; j < 4; ++j)
                        oH0[(row0 + j) * 1024 + col] = (_Float16)acc[mf][nf][j];
                } else {
                    const float bb = bias[col];
                    hfx4 pk;
#pragma unroll
                    for (int j = 0; j < 4; ++j) pk[j] = (_Float16)(acc[mf][nf][j] + bb);
                    *(hfx4*)&oH1[((row0 >> 11) * 1024 + col) * 2048 + (row0 & 2047)] = pk;
                }
            }
        }
    }
}

// ---------------------------------------------------------------------------
// Row softmax over 2048 fp32, write fp16 probs IN PLACE. One block per row.
// ---------------------------------------------------------------------------
__global__ __launch_bounds__(256) void softmax_kernel(float* __restrict__ S)
{
    const long row = blockIdx.x;
    float* r = S + row * 2048;
    const int t = threadIdx.x;

    float4 v0 = *(const float4*)&r[t * 4];
    float4 v1 = *(const float4*)&r[1024 + t * 4];
    float v[8] = {v0.x, v0.y, v0.z, v0.w, v1.x, v1.y, v1.z, v1.w};

    float mx = v[0];
#pragma unroll
    for (int j = 1; j < 8; ++j) mx = fmaxf(mx, v[j]);
#pragma unroll
    for (int o = 32; o; o >>= 1) mx = fmaxf(mx, __shfl_xor(mx, o, 64));

    __shared__ float redm[4];
    __shared__ float reds[4];
    const int w = t >> 6;
    if ((t & 63) == 0) redm[w] = mx;
    __syncthreads();
    mx = fmaxf(fmaxf(redm[0], redm[1]), fmaxf(redm[2], redm[3]));

    float e[8];
    float s = 0.f;
#pragma unroll
    for (int j = 0; j < 8; ++j) {
        e[j] = __expf(v[j] - mx);
        s += e[j];
    }
#pragma unroll
    for (int o = 32; o; o >>= 1) s += __shfl_xor(s, o, 64);
    if ((t & 63) == 0) reds[w] = s;
    __syncthreads();
    s = reds[0] + reds[1] + reds[2] + reds[3];

    const float inv = 1.0f / s;
    hfx4 p0, p1;
#pragma unroll
    for (int j = 0; j < 4; ++j) {
        p0[j] = (_Float16)(e[j] * inv);
        p1[j] = (_Float16)(e[4 + j] * inv);
    }
    _Float16* pr = (_Float16*)r;
    *(hfx4*)&pr[t * 4] = p0;
    *(hfx4*)&pr[1024 + t * 4] = p1;
}

// ---------------------------------------------------------------------------
extern "C" void kernel_launch(void* const* d_in, const int* in_sizes, int n_in,
                              void* d_out, int out_size, void* d_ws, size_t ws_size,
                              hipStream_t stream)
{
    const float* x  = (const float*)d_in[0];
    const float* Wq = (const float*)d_in[1];
    const float* bq = (const float*)d_in[2];
    const float* Wk = (const float*)d_in[3];
    const float* bk = (const float*)d_in[4];   // (folded into softmax-invariant terms)
    const float* Wv = (const float*)d_in[5];
    const float* bv = (const float*)d_in[6];
    float* out = (float*)d_out;
    (void)bk;

    _Float16* xs  = (_Float16*)d_ws;            // [8192][1024] 16 MB
    _Float16* Wvh = xs + 8192ull * 1024;        // [1024][1024] 2 MB
    _Float16* WqT = Wvh + 1024ull * 1024;       // 2 MB
    _Float16* WkT = WqT + 1024ull * 1024;       // 2 MB
    _Float16* Mt  = WkT + 1024ull * 1024;       // Wk^T·Wq fp16, 2 MB
    _Float16* Tt  = Mt + 1024ull * 1024;        // T = x·Mt [8192][1024] 16 MB
    _Float16* Vt  = Tt + 8192ull * 1024;        // [4][1024][2048] 16 MB
    float* S      = (float*)(Vt + 4ull * 1024 * 2048);  // [4][2048][2048] 64 MB
    float* w2     = S + 4ull * 2048 * 2048;     // [1024]
    float* v      = w2 + 1024;                  // [8192]

    dim3 blk(256);

    // 1) small precomputes
    transpose_w_kernel<<<dim3(16, 16, 2), blk, 0, stream>>>(Wq, Wk, WqT, WkT);
    w2_kernel<<<4, blk, 0, stream>>>(bq, Wk, w2);

    // 2) converts: x -> xs (+ v = x·w2), Wv -> Wvh
    conv_all_kernel<<<9216, blk, 0, stream>>>(
        (const float4*)x, xs, (const float4*)Wv, Wvh, w2, v);

    // 3) Mt = Wk^T·Wq  (64 blocks, fp16 out)
    gemm2<2><<<dim3(8, 8, 1), blk, 0, stream>>>(
        WkT, WqT, nullptr, nullptr, nullptr,
        nullptr, Mt, nullptr,
        1024, 1024, 1024, 1024, 1.0f, 0L, 0L, 0L);

    // 4) proj: z=0: T = xs·Mt^T; z=1: V = xs·Wvh^T + bv (transposed out).
    //    Grid 8 x 64 x 2 = 1024 blocks = exactly 2 rounds at 2 blocks/CU.
    gemm2<1><<<dim3(8, 64, 2), blk, 0, stream>>>(
        xs, Mt, Wvh, bv, nullptr,
        nullptr, Tt, Vt,
        1024, 1024, 1024, 0, 1.0f, 0L, 0L, 0L);

    // 5) scores: S_z = T_z·xs_z^T + v[z*2048+col], fp32 out (16x16x4 = 1024 blocks)
    gemm2<0><<<dim3(16, 16, 4), blk, 0, stream>>>(
        Tt, xs, nullptr, nullptr, v,
        S, nullptr, nullptr,
        1024, 1024, 1024, 2048, 1.0f,
        2097152L, 2097152L, 4194304L);

    // 6) softmax (P fp16 in place)
    softmax_kernel<<<2048 * 4, blk, 0, stream>>>(S);

    // 7) PV: out = (1/32)·P·Vt^T, fp32 out (8x16x4 = 512 blocks)
    gemm2<0><<<dim3(8, 16, 4), blk, 0, stream>>>(
        (const _Float16*)S, Vt, nullptr, nullptr, nullptr,
        out, nullptr, nullptr,
        2048, 4096, 2048, 1024, 0.03125f,
        8388608L, 2097152L, 2097152L);
}

// Round 13
// 176.576 us; speedup vs baseline: 1.1513x; 1.1513x over previous
//
#include <hip/hip_runtime.h>

// ---------------------------------------------------------------------------
// Self-attention (B=4, N=2048, D=1024) on MI355X — fp16, round 13:
// REVERT to round-8 (best, 178.5 us) + merged convert dispatch.
// All-plain-fp16 pipeline; every GEMM = proven 2-phase 128^2/BK=64
// counted-vmcnt kernel (T1 XCD remap + T2 both-sides swizzle + T4 counted
// vmcnt + T5 setprio), 64 KB LDS -> 2 blocks/CU.
// absmax floor 4.8828e-4 = 2^-11 (P fp16 quantization), threshold 1.76e-3.
// ---------------------------------------------------------------------------

typedef _Float16 hfx8 __attribute__((ext_vector_type(8)));
typedef _Float16 hfx4 __attribute__((ext_vector_type(4)));
typedef float fx4 __attribute__((ext_vector_type(4)));

__device__ __forceinline__ void load_lds16(const void* g, void* l) {
    __builtin_amdgcn_global_load_lds(
        (const __attribute__((address_space(1))) void*)g,
        (__attribute__((address_space(3))) void*)l, 16, 0, 0);
}

template <int N> __device__ __forceinline__ void vmwait() {
    if constexpr (N == 8) asm volatile("s_waitcnt vmcnt(8)" ::: "memory");
    else asm volatile("s_waitcnt vmcnt(0)" ::: "memory");
}

// bijective XCD-chunked grid remap (T1, m204). Requires nwg % 8 == 0.
__device__ __forceinline__ void xcd_remap(int& x, int& y, int& z) {
    const int gx = gridDim.x, gy = gridDim.y;
    const int lin = blockIdx.x + gx * (blockIdx.y + gy * blockIdx.z);
    const int cpx = (gx * gy * gridDim.z) >> 3;
    const int w = (lin & 7) * cpx + (lin >> 3);
    x = w % gx;
    y = (w / gx) % gy;
    z = w / (gx * gy);
}

// ---------------------------------------------------------------------------
// merged converts: blocks [0,8192) -> x (8M floats), [8192,11264) -> Wq/Wk/Wv
// ---------------------------------------------------------------------------
__global__ __launch_bounds__(256) void conv_all_kernel(
    const float4* __restrict__ x, _Float16* __restrict__ xs,
    const float4* __restrict__ w0, const float4* __restrict__ w1, const float4* __restrict__ w2,
    _Float16* __restrict__ o0, _Float16* __restrict__ o1, _Float16* __restrict__ o2)
{
    const int b = blockIdx.x;
    const float4* in;
    _Float16* out;
    long i;
    if (b < 8192) {
        in = x; out = xs;
        i = (long)b * 256 + threadIdx.x;
    } else {
        const int wi = b - 8192;
        const int wsel = wi >> 10;
        in = wsel == 0 ? w0 : (wsel == 1 ? w1 : w2);
        out = wsel == 0 ? o0 : (wsel == 1 ? o1 : o2);
        i = (long)(wi & 1023) * 256 + threadIdx.x;
    }
    float4 v = in[i];
    hfx4 h;
    h[0] = (_Float16)v.x; h[1] = (_Float16)v.y;
    h[2] = (_Float16)v.z; h[3] = (_Float16)v.w;
    *(hfx4*)&out[i * 4] = h;
}

// ---------------------------------------------------------------------------
// Proven 2-phase pipelined GEMM (R8). BM=BN=128, BK=64, 256 thr = 4 waves
// (2x2), 64 KB LDS -> 2 blocks/CU. Counted-vmcnt double-buffer, raw
// s_barrier only, T2 both-sides swizzle, T5 setprio, T1 XCD remap.
// A [M x K] row-major lda; B [N x K] row-major ldb.
// OMODE 0: fp32 out = alpha*acc -> outF + z*sCz (ldc); B = Bq + z*sBz
// OMODE 1: projections (K=1024): z=0 Q fp16 [8192][1024], z=1 K fp16,
//          z=2 V transposed [4][1024][2048]
// ---------------------------------------------------------------------------
template <int OMODE>
__global__ __launch_bounds__(256, 2) void gemm2(
    const _Float16* __restrict__ A,
    const _Float16* __restrict__ Bq, const _Float16* __restrict__ Bk, const _Float16* __restrict__ Bv,
    const float* __restrict__ bq, const float* __restrict__ bk, const float* __restrict__ bv,
    float* __restrict__ outF, _Float16* __restrict__ oQ, _Float16* __restrict__ oK, _Float16* __restrict__ oV,
    int K, int lda, int ldb, int ldc, float alpha,
    long sAz, long sBz, long sCz)
{
    constexpr int BM = 128, BN = 128, BK = 64;
    constexpr int LPT = 8;   // global_load_lds per thread per K-tile

    __shared__ __attribute__((aligned(16))) _Float16 lds[2][(BM + BN) * BK];

    int bx, by, z;
    xcd_remap(bx, by, z);

    A += (long)z * sAz;
    const _Float16* B = (OMODE == 1) ? (z == 0 ? Bq : (z == 1 ? Bk : Bv))
                                     : Bq + (long)z * sBz;

    const int tid = threadIdx.x;
    const int lane = tid & 63;
    const int wv = tid >> 6;
    const int wr = wv >> 1, wc = wv & 1;   // 2x2 wave grid, 64x64 out each
    const int lr = lane & 15, lk = lane >> 4;

    const long m0 = (long)by * BM;
    const long n0 = (long)bx * BN;

    fx4 acc[4][4] = {};

    // stage K-tile at element offset kt into buffer b. Linear LDS dest;
    // global source col pre-swizzled by the read involution (rule #21).
    auto STAGE = [&](int kt, int b) {
#pragma unroll
        for (int i = 0; i < LPT; ++i) {
            const int c = i * 256 + tid;
            if (i < 4) {                    // A chunks: 128 rows x 8 slots
                const int row = c >> 3, slot = c & 7;
                load_lds16(A + (m0 + row) * (long)lda + kt + ((slot ^ (row & 7)) << 3),
                           &lds[b][c * 8]);
            } else {                        // B chunks
                const int c2 = c - 1024;
                const int row = c2 >> 3, slot = c2 & 7;
                load_lds16(B + (n0 + row) * (long)ldb + kt + ((slot ^ (row & 7)) << 3),
                           &lds[b][BM * BK + c2 * 8]);
            }
        }
    };

    const int NT = K / BK;
    STAGE(0, 0);
    STAGE(BK, 1);
    vmwait<8>();                            // tile 0 landed, tile 1 in flight
    __builtin_amdgcn_s_barrier();
    __builtin_amdgcn_sched_barrier(0);

    const int rA0 = wr * 64 + lr;
    const int rB0 = wc * 64 + lr;
    const int eA = (rA0 & 7) << 3;          // swizzle (row&7 invariant +16q)
    const int eB = (rB0 & 7) << 3;

    for (int t = 0; t < NT; ++t) {
        const _Float16* LA = &lds[t & 1][0];
        const _Float16* LB = LA + BM * BK;

        hfx8 bfr[4][2];
#pragma unroll
        for (int nf = 0; nf < 4; ++nf)
#pragma unroll
            for (int ks = 0; ks < 2; ++ks)
                bfr[nf][ks] = *(const hfx8*)&LB[(rB0 + nf * 16) * BK + ((ks * 32 + lk * 8) ^ eB)];

#pragma unroll
        for (int q = 0; q < 4; ++q) {
            hfx8 afr[2];
#pragma unroll
            for (int ks = 0; ks < 2; ++ks)
                afr[ks] = *(const hfx8*)&LA[(rA0 + q * 16) * BK + ((ks * 32 + lk * 8) ^ eA)];
            __builtin_amdgcn_s_setprio(1);
#pragma unroll
            for (int nf = 0; nf < 4; ++nf)
#pragma unroll
                for (int ks = 0; ks < 2; ++ks)
                    acc[q][nf] = __builtin_amdgcn_mfma_f32_16x16x32_f16(
                        afr[ks], bfr[nf][ks], acc[q][nf], 0, 0, 0);
            __builtin_amdgcn_s_setprio(0);
        }

        __builtin_amdgcn_s_barrier();       // all waves done reading buf (t&1)
        if (t + 2 < NT) {
            STAGE((t + 2) * BK, t & 1);     // refill just-freed buffer
            vmwait<8>();                    // tile t+1 landed; t+2 in flight
        } else {
            vmwait<0>();                    // tail drain
        }
        __builtin_amdgcn_s_barrier();       // all waves see tile t+1 landed
        __builtin_amdgcn_sched_barrier(0);
    }

    // epilogue. D frag: col = lane&15, row = lk*4 + j
#pragma unroll
    for (int mf = 0; mf < 4; ++mf) {
#pragma unroll
        for (int nf = 0; nf < 4; ++nf) {
            const long row0 = m0 + wr * 64 + mf * 16 + lk * 4;
            const long col = n0 + wc * 64 + nf * 16 + lr;
            if constexpr (OMODE == 0) {
                float* oz = outF + (long)z * sCz;
#pragma unroll
                for (int j = 0; j < 4; ++j)
                    oz[(row0 + j) * (long)ldc + col] = alpha * acc[mf][nf][j];
            } else {
                if (z == 0) {
                    const float bb = bq[col];
#pragma unroll
                    for (int j = 0; j < 4; ++j)
                        oQ[(row0 + j) * 1024 + col] = (_Float16)(acc[mf][nf][j] + bb);
                } else if (z == 1) {
                    const float bb = bk[col];
#pragma unroll
                    for (int j = 0; j < 4; ++j)
                        oK[(row0 + j) * 1024 + col] = (_Float16)(acc[mf][nf][j] + bb);
                } else {
                    const float bb = bv[col];
                    hfx4 pk;
#pragma unroll
                    for (int j = 0; j < 4; ++j) pk[j] = (_Float16)(acc[mf][nf][j] + bb);
                    *(hfx4*)&oV[((row0 >> 11) * 1024 + col) * 2048 + (row0 & 2047)] = pk;
                }
            }
        }
    }
}

// ---------------------------------------------------------------------------
// Row softmax over 2048 fp32, write fp16 probs IN PLACE. One block per row.
// ---------------------------------------------------------------------------
__global__ __launch_bounds__(256) void softmax_kernel(float* __restrict__ S)
{
    const long row = blockIdx.x;
    float* r = S + row * 2048;
    const int t = threadIdx.x;

    float4 v0 = *(const float4*)&r[t * 4];
    float4 v1 = *(const float4*)&r[1024 + t * 4];
    float v[8] = {v0.x, v0.y, v0.z, v0.w, v1.x, v1.y, v1.z, v1.w};

    float mx = v[0];
#pragma unroll
    for (int j = 1; j < 8; ++j) mx = fmaxf(mx, v[j]);
#pragma unroll
    for (int o = 32; o; o >>= 1) mx = fmaxf(mx, __shfl_xor(mx, o, 64));

    __shared__ float redm[4];
    __shared__ float reds[4];
    const int w = t >> 6;
    if ((t & 63) == 0) redm[w] = mx;
    __syncthreads();
    mx = fmaxf(fmaxf(redm[0], redm[1]), fmaxf(redm[2], redm[3]));

    float e[8];
    float s = 0.f;
#pragma unroll
    for (int j = 0; j < 8; ++j) {
        e[j] = __expf(v[j] - mx);
        s += e[j];
    }
#pragma unroll
    for (int o = 32; o; o >>= 1) s += __shfl_xor(s, o, 64);
    if ((t & 63) == 0) reds[w] = s;
    __syncthreads();
    s = reds[0] + reds[1] + reds[2] + reds[3];

    const float inv = 1.0f / s;
    hfx4 p0, p1;
#pragma unroll
    for (int j = 0; j < 4; ++j) {
        p0[j] = (_Float16)(e[j] * inv);
        p1[j] = (_Float16)(e[4 + j] * inv);
    }
    _Float16* pr = (_Float16*)r;
    *(hfx4*)&pr[t * 4] = p0;
    *(hfx4*)&pr[1024 + t * 4] = p1;
}

// ---------------------------------------------------------------------------
extern "C" void kernel_launch(void* const* d_in, const int* in_sizes, int n_in,
                              void* d_out, int out_size, void* d_ws, size_t ws_size,
                              hipStream_t stream)
{
    const float* x  = (const float*)d_in[0];
    const float* Wq = (const float*)d_in[1];
    const float* bq = (const float*)d_in[2];
    const float* Wk = (const float*)d_in[3];
    const float* bk = (const float*)d_in[4];
    const float* Wv = (const float*)d_in[5];
    const float* bv = (const float*)d_in[6];
    float* out = (float*)d_out;

    _Float16* xs  = (_Float16*)d_ws;            // [8192][1024] 16 MB
    _Float16* Wqh = xs + 8192ull * 1024;        // [1024][1024] 2 MB each
    _Float16* Wkh = Wqh + 1024ull * 1024;
    _Float16* Wvh = Wkh + 1024ull * 1024;
    _Float16* Qp  = Wvh + 1024ull * 1024;       // [8192][1024] 16 MB
    _Float16* Ks  = Qp + 8192ull * 1024;        // [8192][1024] 16 MB
    _Float16* Vt  = Ks + 8192ull * 1024;        // [4][1024][2048] 16 MB
    float* S      = (float*)(Vt + 4ull * 1024 * 2048);  // [4][2048][2048] 64 MB

    dim3 blk(256);

    // 1) converts (merged single dispatch, plain fp16)
    conv_all_kernel<<<11264, blk, 0, stream>>>(
        (const float4*)x, xs,
        (const float4*)Wq, (const float4*)Wk, (const float4*)Wv, Wqh, Wkh, Wvh);

    // 2) projections: 8 x 64 x 3 = 1536 blocks (3 tail-free rounds), K=1024.
    gemm2<1><<<dim3(8, 64, 3), blk, 0, stream>>>(
        xs, Wqh, Wkh, Wvh, bq, bk, bv,
        nullptr, Qp, Ks, Vt,
        1024, 1024, 1024, 0, 1.0f, 0L, 0L, 0L);

    // 3) scores: Q @ K^T (K=1024), fp32 out, z=4  (16x16x4 = 1024 blocks)
    gemm2<0><<<dim3(16, 16, 4), blk, 0, stream>>>(
        Qp, Ks, nullptr, nullptr, nullptr, nullptr, nullptr,
        S, nullptr, nullptr, nullptr,
        1024, 1024, 1024, 2048, 1.0f,
        2097152L, 2097152L, 4194304L);

    // 4) softmax (P fp16 in place)
    softmax_kernel<<<2048 * 4, blk, 0, stream>>>(S);

    // 5) PV: P @ Vt^T, alpha = 1/32, fp32 out, z=4  (8x16x4 = 512 blocks)
    gemm2<0><<<dim3(8, 16, 4), blk, 0, stream>>>(
        (const _Float16*)S, Vt, nullptr, nullptr, nullptr, nullptr, nullptr,
        out, nullptr, nullptr, nullptr,
        2048, 4096, 2048, 1024, 0.03125f,
        8388608L, 2097152L, 2097152L);
}

// Round 14
// 171.835 us; speedup vs baseline: 1.1831x; 1.0276x over previous
//
#include <hip/hip_runtime.h>

// ---------------------------------------------------------------------------
// Self-attention (B=4, N=2048, D=1024) on MI355X — fp16, round 14:
// R13 (best, 176.6 us) + fp16 score matrix in HBM: scores epilogue writes
// S as fp16 (-32 MB), softmax reads/writes fp16 in place (-32 MB read), PV
// reads fp16 P at lda=2048. GEMM loop byte-identical to the proven 2-phase
// 128^2/BK=64 counted-vmcnt kernel (T1+T2+T4+T5, 64 KB LDS, 2 blocks/CU).
// ---------------------------------------------------------------------------

typedef _Float16 hfx8 __attribute__((ext_vector_type(8)));
typedef _Float16 hfx4 __attribute__((ext_vector_type(4)));
typedef float fx4 __attribute__((ext_vector_type(4)));

__device__ __forceinline__ void load_lds16(const void* g, void* l) {
    __builtin_amdgcn_global_load_lds(
        (const __attribute__((address_space(1))) void*)g,
        (__attribute__((address_space(3))) void*)l, 16, 0, 0);
}

template <int N> __device__ __forceinline__ void vmwait() {
    if constexpr (N == 8) asm volatile("s_waitcnt vmcnt(8)" ::: "memory");
    else asm volatile("s_waitcnt vmcnt(0)" ::: "memory");
}

// bijective XCD-chunked grid remap (T1, m204). Requires nwg % 8 == 0.
__device__ __forceinline__ void xcd_remap(int& x, int& y, int& z) {
    const int gx = gridDim.x, gy = gridDim.y;
    const int lin = blockIdx.x + gx * (blockIdx.y + gy * blockIdx.z);
    const int cpx = (gx * gy * gridDim.z) >> 3;
    const int w = (lin & 7) * cpx + (lin >> 3);
    x = w % gx;
    y = (w / gx) % gy;
    z = w / (gx * gy);
}

// ---------------------------------------------------------------------------
// merged converts: blocks [0,8192) -> x (8M floats), [8192,11264) -> Wq/Wk/Wv
// ---------------------------------------------------------------------------
__global__ __launch_bounds__(256) void conv_all_kernel(
    const float4* __restrict__ x, _Float16* __restrict__ xs,
    const float4* __restrict__ w0, const float4* __restrict__ w1, const float4* __restrict__ w2,
    _Float16* __restrict__ o0, _Float16* __restrict__ o1, _Float16* __restrict__ o2)
{
    const int b = blockIdx.x;
    const float4* in;
    _Float16* out;
    long i;
    if (b < 8192) {
        in = x; out = xs;
        i = (long)b * 256 + threadIdx.x;
    } else {
        const int wi = b - 8192;
        const int wsel = wi >> 10;
        in = wsel == 0 ? w0 : (wsel == 1 ? w1 : w2);
        out = wsel == 0 ? o0 : (wsel == 1 ? o1 : o2);
        i = (long)(wi & 1023) * 256 + threadIdx.x;
    }
    float4 v = in[i];
    hfx4 h;
    h[0] = (_Float16)v.x; h[1] = (_Float16)v.y;
    h[2] = (_Float16)v.z; h[3] = (_Float16)v.w;
    *(hfx4*)&out[i * 4] = h;
}

// ---------------------------------------------------------------------------
// Proven 2-phase pipelined GEMM (R8/R13). BM=BN=128, BK=64, 256 thr = 4
// waves (2x2), 64 KB LDS -> 2 blocks/CU. Counted-vmcnt double-buffer, raw
// s_barrier only, T2 both-sides swizzle, T5 setprio, T1 XCD remap.
// A [M x K] row-major lda; B [N x K] row-major ldb.
// OMODE 0: fp32 out = alpha*acc -> outF + z*sCz (ldc); B = Bq + z*sBz
// OMODE 1: projections (K=1024): z=0 Q fp16 [8192][1024], z=1 K fp16,
//          z=2 V transposed [4][1024][2048]
// OMODE 2: fp16 out = (fp16)(alpha*acc) -> oQ + z*sCz (ldc); B = Bq + z*sBz
// ---------------------------------------------------------------------------
template <int OMODE>
__global__ __launch_bounds__(256, 2) void gemm2(
    const _Float16* __restrict__ A,
    const _Float16* __restrict__ Bq, const _Float16* __restrict__ Bk, const _Float16* __restrict__ Bv,
    const float* __restrict__ bq, const float* __restrict__ bk, const float* __restrict__ bv,
    float* __restrict__ outF, _Float16* __restrict__ oQ, _Float16* __restrict__ oK, _Float16* __restrict__ oV,
    int K, int lda, int ldb, int ldc, float alpha,
    long sAz, long sBz, long sCz)
{
    constexpr int BM = 128, BN = 128, BK = 64;
    constexpr int LPT = 8;   // global_load_lds per thread per K-tile

    __shared__ __attribute__((aligned(16))) _Float16 lds[2][(BM + BN) * BK];

    int bx, by, z;
    xcd_remap(bx, by, z);

    A += (long)z * sAz;
    const _Float16* B = (OMODE == 1) ? (z == 0 ? Bq : (z == 1 ? Bk : Bv))
                                     : Bq + (long)z * sBz;

    const int tid = threadIdx.x;
    const int lane = tid & 63;
    const int wv = tid >> 6;
    const int wr = wv >> 1, wc = wv & 1;   // 2x2 wave grid, 64x64 out each
    const int lr = lane & 15, lk = lane >> 4;

    const long m0 = (long)by * BM;
    const long n0 = (long)bx * BN;

    fx4 acc[4][4] = {};

    // stage K-tile at element offset kt into buffer b. Linear LDS dest;
    // global source col pre-swizzled by the read involution (rule #21).
    auto STAGE = [&](int kt, int b) {
#pragma unroll
        for (int i = 0; i < LPT; ++i) {
            const int c = i * 256 + tid;
            if (i < 4) {                    // A chunks: 128 rows x 8 slots
                const int row = c >> 3, slot = c & 7;
                load_lds16(A + (m0 + row) * (long)lda + kt + ((slot ^ (row & 7)) << 3),
                           &lds[b][c * 8]);
            } else {                        // B chunks
                const int c2 = c - 1024;
                const int row = c2 >> 3, slot = c2 & 7;
                load_lds16(B + (n0 + row) * (long)ldb + kt + ((slot ^ (row & 7)) << 3),
                           &lds[b][BM * BK + c2 * 8]);
            }
        }
    };

    const int NT = K / BK;
    STAGE(0, 0);
    STAGE(BK, 1);
    vmwait<8>();                            // tile 0 landed, tile 1 in flight
    __builtin_amdgcn_s_barrier();
    __builtin_amdgcn_sched_barrier(0);

    const int rA0 = wr * 64 + lr;
    const int rB0 = wc * 64 + lr;
    const int eA = (rA0 & 7) << 3;          // swizzle (row&7 invariant +16q)
    const int eB = (rB0 & 7) << 3;

    for (int t = 0; t < NT; ++t) {
        const _Float16* LA = &lds[t & 1][0];
        const _Float16* LB = LA + BM * BK;

        hfx8 bfr[4][2];
#pragma unroll
        for (int nf = 0; nf < 4; ++nf)
#pragma unroll
            for (int ks = 0; ks < 2; ++ks)
                bfr[nf][ks] = *(const hfx8*)&LB[(rB0 + nf * 16) * BK + ((ks * 32 + lk * 8) ^ eB)];

#pragma unroll
        for (int q = 0; q < 4; ++q) {
            hfx8 afr[2];
#pragma unroll
            for (int ks = 0; ks < 2; ++ks)
                afr[ks] = *(const hfx8*)&LA[(rA0 + q * 16) * BK + ((ks * 32 + lk * 8) ^ eA)];
            __builtin_amdgcn_s_setprio(1);
#pragma unroll
            for (int nf = 0; nf < 4; ++nf)
#pragma unroll
                for (int ks = 0; ks < 2; ++ks)
                    acc[q][nf] = __builtin_amdgcn_mfma_f32_16x16x32_f16(
                        afr[ks], bfr[nf][ks], acc[q][nf], 0, 0, 0);
            __builtin_amdgcn_s_setprio(0);
        }

        __builtin_amdgcn_s_barrier();       // all waves done reading buf (t&1)
        if (t + 2 < NT) {
            STAGE((t + 2) * BK, t & 1);     // refill just-freed buffer
            vmwait<8>();                    // tile t+1 landed; t+2 in flight
        } else {
            vmwait<0>();                    // tail drain
        }
        __builtin_amdgcn_s_barrier();       // all waves see tile t+1 landed
        __builtin_amdgcn_sched_barrier(0);
    }

    // epilogue. D frag: col = lane&15, row = lk*4 + j
#pragma unroll
    for (int mf = 0; mf < 4; ++mf) {
#pragma unroll
        for (int nf = 0; nf < 4; ++nf) {
            const long row0 = m0 + wr * 64 + mf * 16 + lk * 4;
            const long col = n0 + wc * 64 + nf * 16 + lr;
            if constexpr (OMODE == 0) {
                float* oz = outF + (long)z * sCz;
#pragma unroll
                for (int j = 0; j < 4; ++j)
                    oz[(row0 + j) * (long)ldc + col] = alpha * acc[mf][nf][j];
            } else if constexpr (OMODE == 2) {
                _Float16* oz = oQ + (long)z * sCz;
#pragma unroll
                for (int j = 0; j < 4; ++j)
                    oz[(row0 + j) * (long)ldc + col] = (_Float16)(alpha * acc[mf][nf][j]);
            } else {
                if (z == 0) {
                    const float bb = bq[col];
#pragma unroll
                    for (int j = 0; j < 4; ++j)
                        oQ[(row0 + j) * 1024 + col] = (_Float16)(acc[mf][nf][j] + bb);
                } else if (z == 1) {
                    const float bb = bk[col];
#pragma unroll
                    for (int j = 0; j < 4; ++j)
                        oK[(row0 + j) * 1024 + col] = (_Float16)(acc[mf][nf][j] + bb);
                } else {
                    const float bb = bv[col];
                    hfx4 pk;
#pragma unroll
                    for (int j = 0; j < 4; ++j) pk[j] = (_Float16)(acc[mf][nf][j] + bb);
                    *(hfx4*)&oV[((row0 >> 11) * 1024 + col) * 2048 + (row0 & 2047)] = pk;
                }
            }
        }
    }
}

// ---------------------------------------------------------------------------
// Row softmax over 2048 fp16 scores, fp32 math, fp16 probs IN PLACE.
// One block (256 thr) per row; 8 elems (16B) per thread.
// ---------------------------------------------------------------------------
__global__ __launch_bounds__(256) void softmax_kernel(_Float16* __restrict__ S)
{
    const long row = blockIdx.x;
    _Float16* r = S + row * 2048;
    const int t = threadIdx.x;

    const hfx8 hv = *(const hfx8*)&r[t * 8];
    float v[8];
#pragma unroll
    for (int j = 0; j < 8; ++j) v[j] = (float)hv[j];

    float mx = v[0];
#pragma unroll
    for (int j = 1; j < 8; ++j) mx = fmaxf(mx, v[j]);
#pragma unroll
    for (int o = 32; o; o >>= 1) mx = fmaxf(mx, __shfl_xor(mx, o, 64));

    __shared__ float redm[4];
    __shared__ float reds[4];
    const int w = t >> 6;
    if ((t & 63) == 0) redm[w] = mx;
    __syncthreads();
    mx = fmaxf(fmaxf(redm[0], redm[1]), fmaxf(redm[2], redm[3]));

    float e[8];
    float s = 0.f;
#pragma unroll
    for (int j = 0; j < 8; ++j) {
        e[j] = __expf(v[j] - mx);
        s += e[j];
    }
#pragma unroll
    for (int o = 32; o; o >>= 1) s += __shfl_xor(s, o, 64);
    if ((t & 63) == 0) reds[w] = s;
    __syncthreads();
    s = reds[0] + reds[1] + reds[2] + reds[3];

    const float inv = 1.0f / s;
    hfx8 p;
#pragma unroll
    for (int j = 0; j < 8; ++j) p[j] = (_Float16)(e[j] * inv);
    *(hfx8*)&r[t * 8] = p;
}

// ---------------------------------------------------------------------------
extern "C" void kernel_launch(void* const* d_in, const int* in_sizes, int n_in,
                              void* d_out, int out_size, void* d_ws, size_t ws_size,
                              hipStream_t stream)
{
    const float* x  = (const float*)d_in[0];
    const float* Wq = (const float*)d_in[1];
    const float* bq = (const float*)d_in[2];
    const float* Wk = (const float*)d_in[3];
    const float* bk = (const float*)d_in[4];
    const float* Wv = (const float*)d_in[5];
    const float* bv = (const float*)d_in[6];
    float* out = (float*)d_out;

    _Float16* xs  = (_Float16*)d_ws;            // [8192][1024] 16 MB
    _Float16* Wqh = xs + 8192ull * 1024;        // [1024][1024] 2 MB each
    _Float16* Wkh = Wqh + 1024ull * 1024;
    _Float16* Wvh = Wkh + 1024ull * 1024;
    _Float16* Qp  = Wvh + 1024ull * 1024;       // [8192][1024] 16 MB
    _Float16* Ks  = Qp + 8192ull * 1024;        // [8192][1024] 16 MB
    _Float16* Vt  = Ks + 8192ull * 1024;        // [4][1024][2048] 16 MB
    _Float16* Sh  = Vt + 4ull * 1024 * 2048;    // [4][2048][2048] fp16 32 MB

    dim3 blk(256);

    // 1) converts (merged single dispatch, plain fp16)
    conv_all_kernel<<<11264, blk, 0, stream>>>(
        (const float4*)x, xs,
        (const float4*)Wq, (const float4*)Wk, (const float4*)Wv, Wqh, Wkh, Wvh);

    // 2) projections: 8 x 64 x 3 = 1536 blocks (3 tail-free rounds), K=1024.
    gemm2<1><<<dim3(8, 64, 3), blk, 0, stream>>>(
        xs, Wqh, Wkh, Wvh, bq, bk, bv,
        nullptr, Qp, Ks, Vt,
        1024, 1024, 1024, 0, 1.0f, 0L, 0L, 0L);

    // 3) scores: Q @ K^T (K=1024), fp16 out, z=4  (16x16x4 = 1024 blocks)
    gemm2<2><<<dim3(16, 16, 4), blk, 0, stream>>>(
        Qp, Ks, nullptr, nullptr, nullptr, nullptr, nullptr,
        nullptr, Sh, nullptr, nullptr,
        1024, 1024, 1024, 2048, 1.0f,
        2097152L, 2097152L, 4194304L);

    // 4) softmax (fp16 in/out, in place)
    softmax_kernel<<<2048 * 4, blk, 0, stream>>>(Sh);

    // 5) PV: P @ Vt^T, alpha = 1/32, fp32 out, z=4  (8x16x4 = 512 blocks)
    gemm2<0><<<dim3(8, 16, 4), blk, 0, stream>>>(
        Sh, Vt, nullptr, nullptr, nullptr, nullptr, nullptr,
        out, nullptr, nullptr, nullptr,
        2048, 2048, 2048, 1024, 0.03125f,
        4194304L, 2097152L, 2097152L);
}

// Round 15
// 156.656 us; speedup vs baseline: 1.2977x; 1.0969x over previous
//
#include <hip/hip_runtime.h>

// ---------------------------------------------------------------------------
// Self-attention (B=4, N=2048, D=1024) on MI355X — fp16, round 15:
// R14 + FUSED QKV projection: one kernel stages the shared xs A-tile once
// per K-step and runs 3 MFMA sets (Q,K,V) against it — LDS traffic/FLOP
// -33%, A re-fetch eliminated, 512-block tail-free grid. Skeleton = R10's
// proven BK=32 counted-vmcnt double-buffer (conflicts 0). Scores fp16 out,
// fp16 softmax, PV unchanged from R14.
// ---------------------------------------------------------------------------

typedef _Float16 hfx8 __attribute__((ext_vector_type(8)));
typedef _Float16 hfx4 __attribute__((ext_vector_type(4)));
typedef float fx4 __attribute__((ext_vector_type(4)));

__device__ __forceinline__ void load_lds16(const void* g, void* l) {
    __builtin_amdgcn_global_load_lds(
        (const __attribute__((address_space(1))) void*)g,
        (__attribute__((address_space(3))) void*)l, 16, 0, 0);
}

template <int N> __device__ __forceinline__ void vmwait() {
    if constexpr (N == 8) asm volatile("s_waitcnt vmcnt(8)" ::: "memory");
    else asm volatile("s_waitcnt vmcnt(0)" ::: "memory");
}

// bijective XCD-chunked grid remap (T1, m204). Requires nwg % 8 == 0.
__device__ __forceinline__ void xcd_remap(int& x, int& y, int& z) {
    const int gx = gridDim.x, gy = gridDim.y;
    const int lin = blockIdx.x + gx * (blockIdx.y + gy * blockIdx.z);
    const int cpx = (gx * gy * gridDim.z) >> 3;
    const int w = (lin & 7) * cpx + (lin >> 3);
    x = w % gx;
    y = (w / gx) % gy;
    z = w / (gx * gy);
}

// ---------------------------------------------------------------------------
// merged converts: blocks [0,8192) -> x (8M floats), [8192,11264) -> Wq/Wk/Wv
// ---------------------------------------------------------------------------
__global__ __launch_bounds__(256) void conv_all_kernel(
    const float4* __restrict__ x, _Float16* __restrict__ xs,
    const float4* __restrict__ w0, const float4* __restrict__ w1, const float4* __restrict__ w2,
    _Float16* __restrict__ o0, _Float16* __restrict__ o1, _Float16* __restrict__ o2)
{
    const int b = blockIdx.x;
    const float4* in;
    _Float16* out;
    long i;
    if (b < 8192) {
        in = x; out = xs;
        i = (long)b * 256 + threadIdx.x;
    } else {
        const int wi = b - 8192;
        const int wsel = wi >> 10;
        in = wsel == 0 ? w0 : (wsel == 1 ? w1 : w2);
        out = wsel == 0 ? o0 : (wsel == 1 ? o1 : o2);
        i = (long)(wi & 1023) * 256 + threadIdx.x;
    }
    float4 v = in[i];
    hfx4 h;
    h[0] = (_Float16)v.x; h[1] = (_Float16)v.y;
    h[2] = (_Float16)v.z; h[3] = (_Float16)v.w;
    *(hfx4*)&out[i * 4] = h;
}

// ---------------------------------------------------------------------------
// gemmQKV: fused Q/K/V projection. BM=BN=128, BK=32, 256 thr = 4 waves (2x2).
// LDS per buffer: [A 128x32 | Bq 128x32 | Bk | Bv] = 32 KB; x2 = 64 KB
// -> 2 blocks/CU. A-tile staged once per K-step, 3 B-tiles, acc[3][4][4].
// R10's proven counted-vmcnt double-buffer + both-sides swizzle
// (slot ^= (row>>1)&3, 2-way = free) + T5 setprio + T1 XCD remap.
// Outputs: Q fp16 [8192][1024] (+bq), K fp16 [8192][1024] (+bk),
//          V fp16 transposed [4][1024][2048] (+bv).
// ---------------------------------------------------------------------------
__global__ __launch_bounds__(256, 2) void gemmQKV(
    const _Float16* __restrict__ A,
    const _Float16* __restrict__ Bq, const _Float16* __restrict__ Bk, const _Float16* __restrict__ Bv,
    const float* __restrict__ bq, const float* __restrict__ bk, const float* __restrict__ bv,
    _Float16* __restrict__ oQ, _Float16* __restrict__ oK, _Float16* __restrict__ oV)
{
    constexpr int BK = 32;
    __shared__ __attribute__((aligned(16))) _Float16 lds[2][4 * 128 * BK]; // 64 KB

    int bx, by, zz;
    xcd_remap(bx, by, zz);               // gridDim.z == 1 -> zz == 0

    const int tid = threadIdx.x;
    const int lane = tid & 63;
    const int wv = tid >> 6;
    const int wr = wv >> 1, wc = wv & 1; // 2x2 wave grid, 64x64 out each
    const int lr = lane & 15, lk = lane >> 4;

    const long m0 = (long)by * 128;
    const long n0 = (long)bx * 128;

    fx4 acc[3][4][4] = {};               // [output][q][nf], statically indexed

    // stage K-tile at element offset kt into buffer b: A once + 3 B tiles.
    // Linear LDS dest; global source col pre-swizzled by the read
    // involution (rule #21): 16B-slot ^= (row>>1)&3.
    auto STAGE = [&](int kt, int b) {
#pragma unroll
        for (int i = 0; i < 8; ++i) {
            const int slot = tid & 3;
            if (i < 2) {                 // A: 128 rows x 4 slots
                const int row = i * 64 + (tid >> 2);
                load_lds16(A + (m0 + row) * 1024L + kt + ((slot ^ ((row >> 1) & 3)) << 3),
                           &lds[b][row * BK + slot * 8]);
            } else {                     // B: 3 matrices x 128 rows x 4 slots
                const int which = (i - 2) >> 1;          // 0,0,1,1,2,2
                const int row = ((i - 2) & 1) * 64 + (tid >> 2);
                const _Float16* Bsel = which == 0 ? Bq : (which == 1 ? Bk : Bv);
                load_lds16(Bsel + (n0 + row) * 1024L + kt + ((slot ^ ((row >> 1) & 3)) << 3),
                           &lds[b][(1 + which) * 4096 + row * BK + slot * 8]);
            }
        }
    };

    const int NT = 1024 / BK;            // 32
    STAGE(0, 0);
    STAGE(BK, 1);
    vmwait<8>();                         // tile 0 landed, tile 1 in flight
    __builtin_amdgcn_s_barrier();
    __builtin_amdgcn_sched_barrier(0);

    const int rA0 = wr * 64 + lr;
    const int rB0 = wc * 64 + lr;
    const int eA = (((rA0 >> 1) & 3) << 3);  // invariant under +16q
    const int eB = (((rB0 >> 1) & 3) << 3);

    for (int t = 0; t < NT; ++t) {
        const _Float16* L = &lds[t & 1][0];

        hfx8 afr[4];
#pragma unroll
        for (int q = 0; q < 4; ++q)
            afr[q] = *(const hfx8*)&L[(rA0 + q * 16) * BK + ((lk * 8) ^ eA)];

#pragma unroll
        for (int w3 = 0; w3 < 3; ++w3) {
            hfx8 bfr[4];
#pragma unroll
            for (int nf = 0; nf < 4; ++nf)
                bfr[nf] = *(const hfx8*)&L[(1 + w3) * 4096 + (rB0 + nf * 16) * BK + ((lk * 8) ^ eB)];
            __builtin_amdgcn_s_setprio(1);
#pragma unroll
            for (int q = 0; q < 4; ++q)
#pragma unroll
                for (int nf = 0; nf < 4; ++nf)
                    acc[w3][q][nf] = __builtin_amdgcn_mfma_f32_16x16x32_f16(
                        afr[q], bfr[nf], acc[w3][q][nf], 0, 0, 0);
            __builtin_amdgcn_s_setprio(0);
        }

        __builtin_amdgcn_s_barrier();    // all waves done reading buf (t&1)
        if (t + 2 < NT) {
            STAGE((t + 2) * BK, t & 1);  // refill just-freed buffer
            vmwait<8>();                 // tile t+1 landed; t+2 in flight
        } else {
            vmwait<0>();                 // tail drain
        }
        __builtin_amdgcn_s_barrier();    // all waves see tile t+1 landed
        __builtin_amdgcn_sched_barrier(0);
    }

    // epilogue. D frag: col = lane&15, row = lk*4 + j
#pragma unroll
    for (int w3 = 0; w3 < 3; ++w3) {
#pragma unroll
        for (int mf = 0; mf < 4; ++mf) {
#pragma unroll
            for (int nf = 0; nf < 4; ++nf) {
                const long row0 = m0 + wr * 64 + mf * 16 + lk * 4;
                const long col = n0 + wc * 64 + nf * 16 + lr;
                if (w3 == 0) {
                    const float bb = bq[col];
#pragma unroll
                    for (int j = 0; j < 4; ++j)
                        oQ[(row0 + j) * 1024 + col] = (_Float16)(acc[0][mf][nf][j] + bb);
                } else if (w3 == 1) {
                    const float bb = bk[col];
#pragma unroll
                    for (int j = 0; j < 4; ++j)
                        oK[(row0 + j) * 1024 + col] = (_Float16)(acc[1][mf][nf][j] + bb);
                } else {
                    const float bb = bv[col];
                    hfx4 pk;
#pragma unroll
                    for (int j = 0; j < 4; ++j) pk[j] = (_Float16)(acc[2][mf][nf][j] + bb);
                    *(hfx4*)&oV[((row0 >> 11) * 1024 + col) * 2048 + (row0 & 2047)] = pk;
                }
            }
        }
    }
}

// ---------------------------------------------------------------------------
// Proven 2-phase pipelined GEMM (R8/R13/R14). BM=BN=128, BK=64, 256 thr =
// 4 waves (2x2), 64 KB LDS -> 2 blocks/CU. Counted-vmcnt double-buffer,
// raw s_barrier only, T2 both-sides swizzle, T5 setprio, T1 XCD remap.
// A [M x K] row-major lda; B [N x K] row-major ldb; B = Bq + z*sBz.
// OMODE 0: fp32 out = alpha*acc -> outF + z*sCz (ldc)
// OMODE 2: fp16 out = (fp16)(alpha*acc) -> oH + z*sCz (ldc)
// ---------------------------------------------------------------------------
template <int OMODE>
__global__ __launch_bounds__(256, 2) void gemm2(
    const _Float16* __restrict__ A, const _Float16* __restrict__ Bq,
    float* __restrict__ outF, _Float16* __restrict__ oH,
    int K, int lda, int ldb, int ldc, float alpha,
    long sAz, long sBz, long sCz)
{
    constexpr int BM = 128, BN = 128, BK = 64;
    constexpr int LPT = 8;

    __shared__ __attribute__((aligned(16))) _Float16 lds[2][(BM + BN) * BK];

    int bx, by, z;
    xcd_remap(bx, by, z);

    A += (long)z * sAz;
    const _Float16* B = Bq + (long)z * sBz;

    const int tid = threadIdx.x;
    const int lane = tid & 63;
    const int wv = tid >> 6;
    const int wr = wv >> 1, wc = wv & 1;
    const int lr = lane & 15, lk = lane >> 4;

    const long m0 = (long)by * BM;
    const long n0 = (long)bx * BN;

    fx4 acc[4][4] = {};

    auto STAGE = [&](int kt, int b) {
#pragma unroll
        for (int i = 0; i < LPT; ++i) {
            const int c = i * 256 + tid;
            if (i < 4) {
                const int row = c >> 3, slot = c & 7;
                load_lds16(A + (m0 + row) * (long)lda + kt + ((slot ^ (row & 7)) << 3),
                           &lds[b][c * 8]);
            } else {
                const int c2 = c - 1024;
                const int row = c2 >> 3, slot = c2 & 7;
                load_lds16(B + (n0 + row) * (long)ldb + kt + ((slot ^ (row & 7)) << 3),
                           &lds[b][BM * BK + c2 * 8]);
            }
        }
    };

    const int NT = K / BK;
    STAGE(0, 0);
    STAGE(BK, 1);
    vmwait<8>();
    __builtin_amdgcn_s_barrier();
    __builtin_amdgcn_sched_barrier(0);

    const int rA0 = wr * 64 + lr;
    const int rB0 = wc * 64 + lr;
    const int eA = (rA0 & 7) << 3;
    const int eB = (rB0 & 7) << 3;

    for (int t = 0; t < NT; ++t) {
        const _Float16* LA = &lds[t & 1][0];
        const _Float16* LB = LA + BM * BK;

        hfx8 bfr[4][2];
#pragma unroll
        for (int nf = 0; nf < 4; ++nf)
#pragma unroll
            for (int ks = 0; ks < 2; ++ks)
                bfr[nf][ks] = *(const hfx8*)&LB[(rB0 + nf * 16) * BK + ((ks * 32 + lk * 8) ^ eB)];

#pragma unroll
        for (int q = 0; q < 4; ++q) {
            hfx8 afr[2];
#pragma unroll
            for (int ks = 0; ks < 2; ++ks)
                afr[ks] = *(const hfx8*)&LA[(rA0 + q * 16) * BK + ((ks * 32 + lk * 8) ^ eA)];
            __builtin_amdgcn_s_setprio(1);
#pragma unroll
            for (int nf = 0; nf < 4; ++nf)
#pragma unroll
                for (int ks = 0; ks < 2; ++ks)
                    acc[q][nf] = __builtin_amdgcn_mfma_f32_16x16x32_f16(
                        afr[ks], bfr[nf][ks], acc[q][nf], 0, 0, 0);
            __builtin_amdgcn_s_setprio(0);
        }

        __builtin_amdgcn_s_barrier();
        if (t + 2 < NT) {
            STAGE((t + 2) * BK, t & 1);
            vmwait<8>();
        } else {
            vmwait<0>();
        }
        __builtin_amdgcn_s_barrier();
        __builtin_amdgcn_sched_barrier(0);
    }

#pragma unroll
    for (int mf = 0; mf < 4; ++mf) {
#pragma unroll
        for (int nf = 0; nf < 4; ++nf) {
            const long row0 = m0 + wr * 64 + mf * 16 + lk * 4;
            const long col = n0 + wc * 64 + nf * 16 + lr;
            if constexpr (OMODE == 0) {
                float* oz = outF + (long)z * sCz;
#pragma unroll
                for (int j = 0; j < 4; ++j)
                    oz[(row0 + j) * (long)ldc + col] = alpha * acc[mf][nf][j];
            } else {
                _Float16* oz = oH + (long)z * sCz;
#pragma unroll
                for (int j = 0; j < 4; ++j)
                    oz[(row0 + j) * (long)ldc + col] = (_Float16)(alpha * acc[mf][nf][j]);
            }
        }
    }
}

// ---------------------------------------------------------------------------
// Row softmax over 2048 fp16 scores, fp32 math, fp16 probs IN PLACE.
// ---------------------------------------------------------------------------
__global__ __launch_bounds__(256) void softmax_kernel(_Float16* __restrict__ S)
{
    const long row = blockIdx.x;
    _Float16* r = S + row * 2048;
    const int t = threadIdx.x;

    const hfx8 hv = *(const hfx8*)&r[t * 8];
    float v[8];
#pragma unroll
    for (int j = 0; j < 8; ++j) v[j] = (float)hv[j];

    float mx = v[0];
#pragma unroll
    for (int j = 1; j < 8; ++j) mx = fmaxf(mx, v[j]);
#pragma unroll
    for (int o = 32; o; o >>= 1) mx = fmaxf(mx, __shfl_xor(mx, o, 64));

    __shared__ float redm[4];
    __shared__ float reds[4];
    const int w = t >> 6;
    if ((t & 63) == 0) redm[w] = mx;
    __syncthreads();
    mx = fmaxf(fmaxf(redm[0], redm[1]), fmaxf(redm[2], redm[3]));

    float e[8];
    float s = 0.f;
#pragma unroll
    for (int j = 0; j < 8; ++j) {
        e[j] = __expf(v[j] - mx);
        s += e[j];
    }
#pragma unroll
    for (int o = 32; o; o >>= 1) s += __shfl_xor(s, o, 64);
    if ((t & 63) == 0) reds[w] = s;
    __syncthreads();
    s = reds[0] + reds[1] + reds[2] + reds[3];

    const float inv = 1.0f / s;
    hfx8 p;
#pragma unroll
    for (int j = 0; j < 8; ++j) p[j] = (_Float16)(e[j] * inv);
    *(hfx8*)&r[t * 8] = p;
}

// ---------------------------------------------------------------------------
extern "C" void kernel_launch(void* const* d_in, const int* in_sizes, int n_in,
                              void* d_out, int out_size, void* d_ws, size_t ws_size,
                              hipStream_t stream)
{
    const float* x  = (const float*)d_in[0];
    const float* Wq = (const float*)d_in[1];
    const float* bq = (const float*)d_in[2];
    const float* Wk = (const float*)d_in[3];
    const float* bk = (const float*)d_in[4];
    const float* Wv = (const float*)d_in[5];
    const float* bv = (const float*)d_in[6];
    float* out = (float*)d_out;

    _Float16* xs  = (_Float16*)d_ws;            // [8192][1024] 16 MB
    _Float16* Wqh = xs + 8192ull * 1024;        // [1024][1024] 2 MB each
    _Float16* Wkh = Wqh + 1024ull * 1024;
    _Float16* Wvh = Wkh + 1024ull * 1024;
    _Float16* Qp  = Wvh + 1024ull * 1024;       // [8192][1024] 16 MB
    _Float16* Ks  = Qp + 8192ull * 1024;        // [8192][1024] 16 MB
    _Float16* Vt  = Ks + 8192ull * 1024;        // [4][1024][2048] 16 MB
    _Float16* Sh  = Vt + 4ull * 1024 * 2048;    // [4][2048][2048] fp16 32 MB

    dim3 blk(256);

    // 1) converts (merged single dispatch, plain fp16)
    conv_all_kernel<<<11264, blk, 0, stream>>>(
        (const float4*)x, xs,
        (const float4*)Wq, (const float4*)Wk, (const float4*)Wv, Wqh, Wkh, Wvh);

    // 2) fused QKV projection: 8 x 64 = 512 blocks = one tail-free round.
    gemmQKV<<<dim3(8, 64, 1), blk, 0, stream>>>(
        xs, Wqh, Wkh, Wvh, bq, bk, bv, Qp, Ks, Vt);

    // 3) scores: Q @ K^T (K=1024), fp16 out, z=4  (16x16x4 = 1024 blocks)
    gemm2<2><<<dim3(16, 16, 4), blk, 0, stream>>>(
        Qp, Ks, nullptr, Sh,
        1024, 1024, 1024, 2048, 1.0f,
        2097152L, 2097152L, 4194304L);

    // 4) softmax (fp16 in/out, in place)
    softmax_kernel<<<2048 * 4, blk, 0, stream>>>(Sh);

    // 5) PV: P @ Vt^T, alpha = 1/32, fp32 out, z=4  (8x16x4 = 512 blocks)
    gemm2<0><<<dim3(8, 16, 4), blk, 0, stream>>>(
        Sh, Vt, out, nullptr,
        2048, 2048, 2048, 1024, 0.03125f,
        4194304L, 2097152L, 2097152L);
}